// Round 8
// baseline (160.142 us; speedup 1.0000x reference)
//
#include <hip/hip_runtime.h>

#define IN_DIM 256
#define HC     128   // H*C
#define NHEAD  4
#define NEG    0.2f
#define CAP    256   // per-wave LDS edge capacity (gather)
#define AS     264   // LDS row stride (ushorts) for staged A tiles
#define BKT    1024  // dsts per bucket
#define NBMAX  128   // max buckets (n <= 131072)
#define EPT    16    // edges per thread (bucket hist/scatter)
#define BE     4096  // edges per block = 256*EPT

typedef __attribute__((ext_vector_type(8))) short short8v;
typedef __attribute__((ext_vector_type(4))) float f32x4;
typedef __attribute__((ext_vector_type(4))) unsigned short ushort4v;

__device__ __forceinline__ unsigned short bf16_rn(float f) {
    unsigned u = __builtin_bit_cast(unsigned, f);
    return (unsigned short)((u + 0x7fffu + ((u >> 16) & 1u)) >> 16);
}
__device__ __forceinline__ float bf16_to_f32(unsigned short b) {
    unsigned u = ((unsigned)b) << 16;
    return __builtin_bit_cast(float, u);
}
__device__ __forceinline__ float fast_tanh(float x) {
    // tanh(x) = 1 - 2/(exp(2x)+1); rcp err ~1e-5, saturates correctly at +/-1
    float t = __expf(2.f * x);
    return fmaf(-2.f, __builtin_amdgcn_rcpf(t + 1.f), 1.f);
}

// ---------------- pack W (hi bf16) into MFMA fragment order ----------------
__global__ void pack_w_kernel(const float* __restrict__ W,
                              unsigned short* __restrict__ w_hi) {
    int t = blockIdx.x * 256 + threadIdx.x;
    if (t >= 8 * 8 * 64) return;
    int l  = t & 63;
    int ct = (t >> 6) & 7;
    int s  = t >> 9;
    int kbase = s * 32 + (l >> 4) * 8;
    int col   = ct * 16 + (l & 15);
    size_t base = (size_t)t * 8;
#pragma unroll
    for (int e = 0; e < 8; ++e)
        w_hi[base + e] = bf16_rn(W[(size_t)(kbase + e) * HC + col]);
}

// ---------------- GEMM: h = x @ W via bf16 MFMA, x staged hi/lo in LDS ----------------
__global__ __launch_bounds__(512) void gemm_mfma_kernel(const float* __restrict__ x,
                                                        const unsigned short* __restrict__ w_hi,
                                                        const float* __restrict__ a_src,
                                                        const float* __restrict__ a_dst,
                                                        unsigned short* __restrict__ h_bf,
                                                        float* __restrict__ alpha_s,
                                                        float* __restrict__ alpha_d, int n) {
    __shared__ unsigned short s_hi[64][AS];
    __shared__ unsigned short s_lo[64][AS];
    __shared__ float pS[64][4];
    __shared__ float pD[64][4];

    const int tid = threadIdx.x;
    const int l   = tid & 63;
    const int wv  = tid >> 6;
    const int row0 = blockIdx.x * 64;

    const float4* x4 = reinterpret_cast<const float4*>(x);
#pragma unroll
    for (int i = 0; i < 8; ++i) {
        int f = tid + i * 512;
        int row = f >> 6, c4 = f & 63;
        float4 v = make_float4(0.f, 0.f, 0.f, 0.f);
        if (row0 + row < n) v = x4[(size_t)(row0 + row) * 64 + c4];
        float e[4] = {v.x, v.y, v.z, v.w};
        ushort4v hi, lo;
#pragma unroll
        for (int q = 0; q < 4; ++q) {
            unsigned short h16 = bf16_rn(e[q]);
            hi[q] = h16;
            lo[q] = bf16_rn(e[q] - bf16_to_f32(h16));
        }
        *reinterpret_cast<ushort4v*>(&s_hi[row][c4 * 4]) = hi;
        *reinterpret_cast<ushort4v*>(&s_lo[row][c4 * 4]) = lo;
    }
    __syncthreads();

    const int ct_g = wv & 3;
    const int rt_g = wv >> 2;
    const int rrow = l & 15;
    const int koff = (l >> 4) * 8;

    f32x4 acc[2][2];
#pragma unroll
    for (int a = 0; a < 2; ++a)
#pragma unroll
        for (int b = 0; b < 2; ++b) acc[a][b] = (f32x4){0.f, 0.f, 0.f, 0.f};

    for (int s = 0; s < 8; ++s) {
        short8v bh[2];
#pragma unroll
        for (int c = 0; c < 2; ++c) {
            int ct = ct_g * 2 + c;
            bh[c] = *reinterpret_cast<const short8v*>(w_hi + ((size_t)(s * 8 + ct) * 64 + l) * 8);
        }
#pragma unroll
        for (int r = 0; r < 2; ++r) {
            int arow = rt_g * 32 + r * 16 + rrow;
            short8v ah = *reinterpret_cast<const short8v*>(&s_hi[arow][koff + s * 32]);
            short8v al = *reinterpret_cast<const short8v*>(&s_lo[arow][koff + s * 32]);
#pragma unroll
            for (int c = 0; c < 2; ++c) {
                acc[r][c] = __builtin_amdgcn_mfma_f32_16x16x32_bf16(ah, bh[c], acc[r][c], 0, 0, 0);
                acc[r][c] = __builtin_amdgcn_mfma_f32_16x16x32_bf16(al, bh[c], acc[r][c], 0, 0, 0);
            }
        }
    }

#pragma unroll
    for (int r = 0; r < 2; ++r) {
#pragma unroll
        for (int c = 0; c < 2; ++c) {
            int col = (ct_g * 2 + c) * 16 + (l & 15);
#pragma unroll
            for (int q = 0; q < 4; ++q) {
                int row = row0 + rt_g * 32 + r * 16 + (l >> 4) * 4 + q;
                if (row < n) h_bf[(size_t)row * HC + col] = bf16_rn(acc[r][c][q]);
            }
        }
    }

    float asc[2], adc[2];
#pragma unroll
    for (int c = 0; c < 2; ++c) {
        int col = (ct_g * 2 + c) * 16 + (l & 15);
        asc[c] = a_src[col];
        adc[c] = a_dst[col];
    }
#pragma unroll
    for (int r = 0; r < 2; ++r) {
#pragma unroll
        for (int q = 0; q < 4; ++q) {
            float vS = acc[r][0][q] * asc[0] + acc[r][1][q] * asc[1];
            float vD = acc[r][0][q] * adc[0] + acc[r][1][q] * adc[1];
#pragma unroll
            for (int m = 1; m < 16; m <<= 1) {
                vS += __shfl_xor(vS, m);
                vD += __shfl_xor(vD, m);
            }
            if ((l & 15) == 0) {
                int rl = rt_g * 32 + r * 16 + (l >> 4) * 4 + q;
                pS[rl][ct_g] = vS;
                pD[rl][ct_g] = vD;
            }
        }
    }
    __syncthreads();
    if (tid < 256) {
        int rl = tid >> 2, h = tid & 3;
        int row = row0 + rl;
        if (row < n) {
            alpha_s[(size_t)row * 4 + h] = pS[rl][h];
            alpha_d[(size_t)row * 4 + h] = pD[rl][h];
        }
    }
}

// ---------------- CSR build: two-level counting sort by dst ----------------
__global__ __launch_bounds__(256) void bucket_hist_kernel(const int* __restrict__ ei,
                                                          int* __restrict__ bucket_cnt,
                                                          int E, int nb) {
    __shared__ int lh[NBMAX];
    int tid = threadIdx.x;
    if (tid < NBMAX) lh[tid] = 0;
    __syncthreads();
    int base = blockIdx.x * BE;
#pragma unroll
    for (int i = 0; i < EPT; ++i) {
        int e = base + i * 256 + tid;
        if (e < E) atomicAdd(&lh[ei[E + e] >> 10], 1);
    }
    __syncthreads();
    if (tid < nb && lh[tid]) atomicAdd(&bucket_cnt[tid], lh[tid]);
}

__global__ __launch_bounds__(128) void bucket_scan_kernel(const int* __restrict__ bucket_cnt,
                                                          int* __restrict__ bucket_base,
                                                          int* __restrict__ bucket_cursor,
                                                          int nb) {
    __shared__ int ws0[1];
    int t = threadIdx.x;
    int v = (t < nb) ? bucket_cnt[t] : 0;
    int lane = t & 63, wd = t >> 6;
    int x = v;
#pragma unroll
    for (int off = 1; off < 64; off <<= 1) {
        int y = __shfl_up(x, off);
        if (lane >= off) x += y;
    }
    if (wd == 0 && lane == 63) ws0[0] = x;
    __syncthreads();
    int wo = wd ? ws0[0] : 0;
    int excl = wo + x - v;
    if (t < nb) { bucket_base[t] = excl; bucket_cursor[t] = excl; }
    if (t == 127) bucket_base[nb] = wo + x;   // total = E
}

__global__ __launch_bounds__(256) void bucket_scatter_kernel(const int* __restrict__ ei,
                                                             int* __restrict__ bucket_cursor,
                                                             unsigned* __restrict__ bucket_data,
                                                             int E, int nb) {
    __shared__ int lh[NBMAX];
    __shared__ int lofs[NBMAX];
    __shared__ int gofs[NBMAX];
    __shared__ int ws0[1];
    __shared__ unsigned buf[BE];

    int tid = threadIdx.x;
    if (tid < NBMAX) lh[tid] = 0;
    __syncthreads();

    int base = blockIdx.x * BE;
    int bb[EPT]; unsigned wv[EPT]; int rr[EPT];
#pragma unroll
    for (int i = 0; i < EPT; ++i) {
        int e = base + i * 256 + tid;
        if (e < E) {
            int src = ei[e];
            int dst = ei[E + e];
            bb[i] = dst >> 10;
            wv[i] = (unsigned)src | ((unsigned)(dst & 1023) << 17);
            rr[i] = atomicAdd(&lh[bb[i]], 1);
        } else bb[i] = -1;
    }
    __syncthreads();

    int v_ = 0, x_ = 0;
    int lane = tid & 63, wd = tid >> 6;
    if (tid < NBMAX) {
        v_ = lh[tid]; x_ = v_;
#pragma unroll
        for (int off = 1; off < 64; off <<= 1) {
            int y = __shfl_up(x_, off);
            if (lane >= off) x_ += y;
        }
        if (wd == 0 && lane == 63) ws0[0] = x_;
    }
    __syncthreads();
    if (tid < NBMAX) {
        int wo = wd ? ws0[0] : 0;
        lofs[tid] = wo + x_ - v_;
    }
    __syncthreads();

#pragma unroll
    for (int i = 0; i < EPT; ++i)
        if (bb[i] >= 0) buf[lofs[bb[i]] + rr[i]] = wv[i];
    if (tid < nb) gofs[tid] = lh[tid] ? atomicAdd(&bucket_cursor[tid], lh[tid]) : 0;
    __syncthreads();

    int wid = tid >> 6;
    for (int bk = wid; bk < nb; bk += 4) {
        int lo = lofs[bk], cnt = lh[bk], g = gofs[bk];
        for (int j = lane; j < cnt; j += 64)
            bucket_data[g + j] = buf[lo + j];
    }
}

__global__ __launch_bounds__(1024) void bucket_build_kernel(const int* __restrict__ bucket_base,
                                                            const unsigned* __restrict__ bucket_data,
                                                            int* __restrict__ deg,
                                                            int* __restrict__ row_start,
                                                            int* __restrict__ csr_src, int n) {
    __shared__ int lc[BKT];
    __shared__ int sc[BKT];
    __shared__ int wsum[16];

    int b = blockIdx.x;
    int base = bucket_base[b];
    int end  = bucket_base[b + 1];
    int t = threadIdx.x;

    lc[t] = 0;
    __syncthreads();
    for (int i = base + t; i < end; i += 1024)
        atomicAdd(&lc[bucket_data[i] >> 17], 1);
    __syncthreads();

    int val = lc[t];
    int lane = t & 63, wd = t >> 6;
    int x = val;
#pragma unroll
    for (int off = 1; off < 64; off <<= 1) {
        int y = __shfl_up(x, off);
        if (lane >= off) x += y;
    }
    if (lane == 63) wsum[wd] = x;
    __syncthreads();
    if (wd == 0 && lane < 16) {
        int y = wsum[lane];
#pragma unroll
        for (int off = 1; off < 16; off <<= 1) {
            int z = __shfl_up(y, off);
            if (lane >= off) y += z;
        }
        wsum[lane] = y;
    }
    __syncthreads();
    int wo = wd ? wsum[wd - 1] : 0;
    int excl = wo + x - val;
    sc[t] = excl;
    int v = b * BKT + t;
    if (v < n) { deg[v] = val; row_start[v] = base + excl; }
    lc[t] = 0;
    __syncthreads();

    for (int i = base + t; i < end; i += 1024) {
        unsigned w = bucket_data[i];
        int d = w >> 17;
        int src = (int)(w & 0x1FFFFu);
        int p = atomicAdd(&lc[d], 1);
        csr_src[base + sc[d] + p] = src;
    }
}

// ---------------- fused gather: softmax + weighted sum + bias + tanh ----------------
// one wave per dst node; lane owns channels {2*lane, 2*lane+1}; head = lane>>4.
// pass 1: head-grouped (each 16-lane group computes its own head's weights).
__global__ __launch_bounds__(256) void gather_kernel(const int* __restrict__ row_start,
                                                     const int* __restrict__ deg,
                                                     const int* __restrict__ csr_src,
                                                     const float* __restrict__ alpha_s,
                                                     const float* __restrict__ alpha_d,
                                                     const unsigned short* __restrict__ h_bf,
                                                     const float* __restrict__ bias,
                                                     float* __restrict__ out, int n) {
    __shared__ float wbuf[4][NHEAD][CAP + 4];   // +4 pad: head planes on distinct banks
    __shared__ int   sbuf[4][CAP];
    int lane = threadIdx.x & 63;
    int wid  = threadIdx.x >> 6;
    int v = blockIdx.x * 4 + wid;
    if (v >= n) return;
    int start = row_start[v];
    int cnt = deg[v];
    int head = lane >> 4;
    int sub  = lane & 15;
    float* wp = wbuf[wid][head];
    int* sp = sbuf[wid];

    float adH = alpha_d[(size_t)v * 4 + head];

    // pass 1: per-head exp weights -> LDS plane; per-lane partial denominator
    float s = 0.f;
    for (int j = sub; j < cnt; j += 16) {
        int src = csr_src[start + j];
        float as = alpha_s[(size_t)src * 4 + head];
        float e = as + adH;
        e = e > 0.f ? e : NEG * e;
        float p = __expf(e);
        if (j < CAP) {
            wp[j] = p;
            if (head == 0) sp[j] = src;
        }
        s += p;
    }
#pragma unroll
    for (int off = 1; off < 16; off <<= 1) s += __shfl_xor(s, off);

    // self-loop term (per-lane head)
    float asH = alpha_s[(size_t)v * 4 + head];
    float es = asH + adH;
    es = es > 0.f ? es : NEG * es;
    float pself = __expf(es);
    s += pself;
    float invH = __builtin_amdgcn_rcpf(s + 1e-16f);

    // pass 2: unnormalized accumulate (normalize at the end), x4 unroll, vector LDS reads
    float accx = 0.f, accy = 0.f;
    const unsigned* hb = reinterpret_cast<const unsigned*>(h_bf);
    int m = cnt < CAP ? cnt : CAP;
    int j = 0;
    for (; j + 4 <= m; j += 4) {
        int4   s4 = *reinterpret_cast<const int4*>(&sp[j]);    // broadcast
        float4 w4 = *reinterpret_cast<const float4*>(&wp[j]);  // per-group broadcast
        unsigned hA = hb[((unsigned)s4.x << 6) + lane];
        unsigned hB = hb[((unsigned)s4.y << 6) + lane];
        unsigned hC = hb[((unsigned)s4.z << 6) + lane];
        unsigned hD = hb[((unsigned)s4.w << 6) + lane];
        accx = fmaf(w4.x, bf16_to_f32((unsigned short)(hA & 0xffffu)), accx);
        accy = fmaf(w4.x, bf16_to_f32((unsigned short)(hA >> 16)),     accy);
        accx = fmaf(w4.y, bf16_to_f32((unsigned short)(hB & 0xffffu)), accx);
        accy = fmaf(w4.y, bf16_to_f32((unsigned short)(hB >> 16)),     accy);
        accx = fmaf(w4.z, bf16_to_f32((unsigned short)(hC & 0xffffu)), accx);
        accy = fmaf(w4.z, bf16_to_f32((unsigned short)(hC >> 16)),     accy);
        accx = fmaf(w4.w, bf16_to_f32((unsigned short)(hD & 0xffffu)), accx);
        accy = fmaf(w4.w, bf16_to_f32((unsigned short)(hD >> 16)),     accy);
    }
    for (; j < m; ++j) {
        int src = sp[j];
        float w = wp[j];
        unsigned hv = hb[((unsigned)src << 6) + lane];
        accx = fmaf(w, bf16_to_f32((unsigned short)(hv & 0xffffu)), accx);
        accy = fmaf(w, bf16_to_f32((unsigned short)(hv >> 16)),     accy);
    }
    for (; j < cnt; ++j) {   // overflow fallback (deg > CAP): recompute weight
        int src = csr_src[start + j];
        float as = alpha_s[(size_t)src * 4 + head];
        float e = as + adH;
        e = e > 0.f ? e : NEG * e;
        float w = __expf(e);
        unsigned hv = hb[((unsigned)src << 6) + lane];
        accx = fmaf(w, bf16_to_f32((unsigned short)(hv & 0xffffu)), accx);
        accy = fmaf(w, bf16_to_f32((unsigned short)(hv >> 16)),     accy);
    }
    {
        unsigned hv = hb[((unsigned)v << 6) + lane];
        accx = fmaf(pself, bf16_to_f32((unsigned short)(hv & 0xffffu)), accx);
        accy = fmaf(pself, bf16_to_f32((unsigned short)(hv >> 16)),     accy);
    }
    float2 b = reinterpret_cast<const float2*>(bias)[lane];
    float2 o;
    o.x = fast_tanh(fmaf(accx, invH, b.x));
    o.y = fast_tanh(fmaf(accy, invH, b.y));
    reinterpret_cast<float2*>(out)[(size_t)v * 64 + lane] = o;
}

extern "C" void kernel_launch(void* const* d_in, const int* in_sizes, int n_in,
                              void* d_out, int out_size, void* d_ws, size_t ws_size,
                              hipStream_t stream) {
    const float* x     = (const float*)d_in[0];
    const float* W     = (const float*)d_in[1];
    const float* a_src = (const float*)d_in[2];
    const float* a_dst = (const float*)d_in[3];
    const float* bias  = (const float*)d_in[4];
    const int*   ei    = (const int*)d_in[5];

    const int n = in_sizes[0] / IN_DIM;        // 100000
    const int E = in_sizes[5] / 2;             // 1000000
    const int nb = (n + BKT - 1) / BKT;        // 98

    float* ws = (float*)d_ws;
    size_t off = 0;
    unsigned short* h_bf = (unsigned short*)(ws + off); off += (size_t)n * HC / 2;
    float* alpha_s = ws + off; off += (size_t)n * NHEAD;
    float* alpha_d = ws + off; off += (size_t)n * NHEAD;
    unsigned short* w_hi = (unsigned short*)(ws + off); off += 16384;
    int* ibase        = (int*)(ws + off);
    int* deg          = ibase;                        // n
    int* row_start    = ibase + n;                    // n
    int* bucket_cnt   = ibase + 2 * (size_t)n;        // NBMAX
    int* bucket_base  = bucket_cnt + NBMAX;           // NBMAX+1
    int* bucket_cursor= bucket_base + NBMAX + 1;      // NBMAX
    unsigned* bucket_data = (unsigned*)(bucket_cursor + NBMAX);  // E
    int* csr_src      = (int*)(bucket_data + E);      // E

    float* out = (float*)d_out;

    const int nblkE = (E + BE - 1) / BE;

    hipMemsetAsync(bucket_cnt, 0, NBMAX * sizeof(int), stream);

    pack_w_kernel<<<16, 256, 0, stream>>>(W, w_hi);
    gemm_mfma_kernel<<<(n + 63) / 64, 512, 0, stream>>>(x, w_hi, a_src, a_dst,
                                                        h_bf, alpha_s, alpha_d, n);

    bucket_hist_kernel<<<nblkE, 256, 0, stream>>>(ei, bucket_cnt, E, nb);
    bucket_scan_kernel<<<1, 128, 0, stream>>>(bucket_cnt, bucket_base, bucket_cursor, nb);
    bucket_scatter_kernel<<<nblkE, 256, 0, stream>>>(ei, bucket_cursor, bucket_data, E, nb);
    bucket_build_kernel<<<nb, 1024, 0, stream>>>(bucket_base, bucket_data,
                                                 deg, row_start, csr_src, n);

    gather_kernel<<<(n + 3) / 4, 256, 0, stream>>>(row_start, deg, csr_src,
                                                   alpha_s, alpha_d, h_bf, bias, out, n);
}

// Round 9
// 153.320 us; speedup vs baseline: 1.0445x; 1.0445x over previous
//
#include <hip/hip_runtime.h>

#define IN_DIM 256
#define HC     128   // H*C
#define NHEAD  4
#define NEG    0.2f
#define AS     264   // LDS row stride (ushorts) for staged A tiles
#define BKT    1024  // dsts per bucket
#define NBMAX  128   // max buckets (n <= 131072)
#define EPT    16    // edges per thread (bucket hist/scatter)
#define BE     4096  // edges per block = 256*EPT

typedef __attribute__((ext_vector_type(8))) short short8v;
typedef __attribute__((ext_vector_type(4))) float f32x4;
typedef __attribute__((ext_vector_type(4))) unsigned short ushort4v;

__device__ __forceinline__ unsigned short bf16_rn(float f) {
    unsigned u = __builtin_bit_cast(unsigned, f);
    return (unsigned short)((u + 0x7fffu + ((u >> 16) & 1u)) >> 16);
}
__device__ __forceinline__ float bf16_to_f32(unsigned short b) {
    unsigned u = ((unsigned)b) << 16;
    return __builtin_bit_cast(float, u);
}
__device__ __forceinline__ float bf16_lo(unsigned v) {
    return __builtin_bit_cast(float, v << 16);
}
__device__ __forceinline__ float bf16_hi(unsigned v) {
    return __builtin_bit_cast(float, v & 0xffff0000u);
}
__device__ __forceinline__ float fast_tanh(float x) {
    float t = __expf(2.f * x);
    return fmaf(-2.f, __builtin_amdgcn_rcpf(t + 1.f), 1.f);
}
__device__ __forceinline__ float lrelu(float e) {
    return fmaxf(e, NEG * e);
}

// ---------------- pack W (hi bf16) into MFMA fragment order ----------------
__global__ void pack_w_kernel(const float* __restrict__ W,
                              unsigned short* __restrict__ w_hi) {
    int t = blockIdx.x * 256 + threadIdx.x;
    if (t >= 8 * 8 * 64) return;
    int l  = t & 63;
    int ct = (t >> 6) & 7;
    int s  = t >> 9;
    int kbase = s * 32 + (l >> 4) * 8;
    int col   = ct * 16 + (l & 15);
    size_t base = (size_t)t * 8;
#pragma unroll
    for (int e = 0; e < 8; ++e)
        w_hi[base + e] = bf16_rn(W[(size_t)(kbase + e) * HC + col]);
}

// ---------------- GEMM: h = x @ W via bf16 MFMA, x staged hi/lo in LDS ----------------
__global__ __launch_bounds__(512) void gemm_mfma_kernel(const float* __restrict__ x,
                                                        const unsigned short* __restrict__ w_hi,
                                                        const float* __restrict__ a_src,
                                                        const float* __restrict__ a_dst,
                                                        unsigned short* __restrict__ h_bf,
                                                        float* __restrict__ alpha_s,
                                                        float* __restrict__ alpha_d, int n) {
    __shared__ unsigned short s_hi[64][AS];
    __shared__ unsigned short s_lo[64][AS];
    __shared__ float pS[64][4];
    __shared__ float pD[64][4];

    const int tid = threadIdx.x;
    const int l   = tid & 63;
    const int wv  = tid >> 6;
    const int row0 = blockIdx.x * 64;

    const float4* x4 = reinterpret_cast<const float4*>(x);
#pragma unroll
    for (int i = 0; i < 8; ++i) {
        int f = tid + i * 512;
        int row = f >> 6, c4 = f & 63;
        float4 v = make_float4(0.f, 0.f, 0.f, 0.f);
        if (row0 + row < n) v = x4[(size_t)(row0 + row) * 64 + c4];
        float e[4] = {v.x, v.y, v.z, v.w};
        ushort4v hi, lo;
#pragma unroll
        for (int q = 0; q < 4; ++q) {
            unsigned short h16 = bf16_rn(e[q]);
            hi[q] = h16;
            lo[q] = bf16_rn(e[q] - bf16_to_f32(h16));
        }
        *reinterpret_cast<ushort4v*>(&s_hi[row][c4 * 4]) = hi;
        *reinterpret_cast<ushort4v*>(&s_lo[row][c4 * 4]) = lo;
    }
    __syncthreads();

    const int ct_g = wv & 3;
    const int rt_g = wv >> 2;
    const int rrow = l & 15;
    const int koff = (l >> 4) * 8;

    f32x4 acc[2][2];
#pragma unroll
    for (int a = 0; a < 2; ++a)
#pragma unroll
        for (int b = 0; b < 2; ++b) acc[a][b] = (f32x4){0.f, 0.f, 0.f, 0.f};

    for (int s = 0; s < 8; ++s) {
        short8v bh[2];
#pragma unroll
        for (int c = 0; c < 2; ++c) {
            int ct = ct_g * 2 + c;
            bh[c] = *reinterpret_cast<const short8v*>(w_hi + ((size_t)(s * 8 + ct) * 64 + l) * 8);
        }
#pragma unroll
        for (int r = 0; r < 2; ++r) {
            int arow = rt_g * 32 + r * 16 + rrow;
            short8v ah = *reinterpret_cast<const short8v*>(&s_hi[arow][koff + s * 32]);
            short8v al = *reinterpret_cast<const short8v*>(&s_lo[arow][koff + s * 32]);
#pragma unroll
            for (int c = 0; c < 2; ++c) {
                acc[r][c] = __builtin_amdgcn_mfma_f32_16x16x32_bf16(ah, bh[c], acc[r][c], 0, 0, 0);
                acc[r][c] = __builtin_amdgcn_mfma_f32_16x16x32_bf16(al, bh[c], acc[r][c], 0, 0, 0);
            }
        }
    }

#pragma unroll
    for (int r = 0; r < 2; ++r) {
#pragma unroll
        for (int c = 0; c < 2; ++c) {
            int col = (ct_g * 2 + c) * 16 + (l & 15);
#pragma unroll
            for (int q = 0; q < 4; ++q) {
                int row = row0 + rt_g * 32 + r * 16 + (l >> 4) * 4 + q;
                if (row < n) h_bf[(size_t)row * HC + col] = bf16_rn(acc[r][c][q]);
            }
        }
    }

    float asc[2], adc[2];
#pragma unroll
    for (int c = 0; c < 2; ++c) {
        int col = (ct_g * 2 + c) * 16 + (l & 15);
        asc[c] = a_src[col];
        adc[c] = a_dst[col];
    }
#pragma unroll
    for (int r = 0; r < 2; ++r) {
#pragma unroll
        for (int q = 0; q < 4; ++q) {
            float vS = acc[r][0][q] * asc[0] + acc[r][1][q] * asc[1];
            float vD = acc[r][0][q] * adc[0] + acc[r][1][q] * adc[1];
#pragma unroll
            for (int m = 1; m < 16; m <<= 1) {
                vS += __shfl_xor(vS, m);
                vD += __shfl_xor(vD, m);
            }
            if ((l & 15) == 0) {
                int rl = rt_g * 32 + r * 16 + (l >> 4) * 4 + q;
                pS[rl][ct_g] = vS;
                pD[rl][ct_g] = vD;
            }
        }
    }
    __syncthreads();
    if (tid < 256) {
        int rl = tid >> 2, h = tid & 3;
        int row = row0 + rl;
        if (row < n) {
            alpha_s[(size_t)row * 4 + h] = pS[rl][h];
            alpha_d[(size_t)row * 4 + h] = pD[rl][h];
        }
    }
}

// ---------------- CSR build: two-level counting sort by dst ----------------
__global__ __launch_bounds__(256) void bucket_hist_kernel(const int* __restrict__ ei,
                                                          int* __restrict__ bucket_cnt,
                                                          int E, int nb) {
    __shared__ int lh[NBMAX];
    int tid = threadIdx.x;
    if (tid < NBMAX) lh[tid] = 0;
    __syncthreads();
    int base = blockIdx.x * BE;
#pragma unroll
    for (int i = 0; i < EPT; ++i) {
        int e = base + i * 256 + tid;
        if (e < E) atomicAdd(&lh[ei[E + e] >> 10], 1);
    }
    __syncthreads();
    if (tid < nb && lh[tid]) atomicAdd(&bucket_cnt[tid], lh[tid]);
}

__global__ __launch_bounds__(128) void bucket_scan_kernel(const int* __restrict__ bucket_cnt,
                                                          int* __restrict__ bucket_base,
                                                          int* __restrict__ bucket_cursor,
                                                          int nb) {
    __shared__ int ws0[1];
    int t = threadIdx.x;
    int v = (t < nb) ? bucket_cnt[t] : 0;
    int lane = t & 63, wd = t >> 6;
    int x = v;
#pragma unroll
    for (int off = 1; off < 64; off <<= 1) {
        int y = __shfl_up(x, off);
        if (lane >= off) x += y;
    }
    if (wd == 0 && lane == 63) ws0[0] = x;
    __syncthreads();
    int wo = wd ? ws0[0] : 0;
    int excl = wo + x - v;
    if (t < nb) { bucket_base[t] = excl; bucket_cursor[t] = excl; }
    if (t == 127) bucket_base[nb] = wo + x;   // total = E
}

__global__ __launch_bounds__(256) void bucket_scatter_kernel(const int* __restrict__ ei,
                                                             int* __restrict__ bucket_cursor,
                                                             unsigned* __restrict__ bucket_data,
                                                             int E, int nb) {
    __shared__ int lh[NBMAX];
    __shared__ int lofs[NBMAX];
    __shared__ int gofs[NBMAX];
    __shared__ int ws0[1];
    __shared__ unsigned buf[BE];

    int tid = threadIdx.x;
    if (tid < NBMAX) lh[tid] = 0;
    __syncthreads();

    int base = blockIdx.x * BE;
    int bb[EPT]; unsigned wv[EPT]; int rr[EPT];
#pragma unroll
    for (int i = 0; i < EPT; ++i) {
        int e = base + i * 256 + tid;
        if (e < E) {
            int src = ei[e];
            int dst = ei[E + e];
            bb[i] = dst >> 10;
            wv[i] = (unsigned)src | ((unsigned)(dst & 1023) << 17);
            rr[i] = atomicAdd(&lh[bb[i]], 1);
        } else bb[i] = -1;
    }
    __syncthreads();

    int v_ = 0, x_ = 0;
    int lane = tid & 63, wd = tid >> 6;
    if (tid < NBMAX) {
        v_ = lh[tid]; x_ = v_;
#pragma unroll
        for (int off = 1; off < 64; off <<= 1) {
            int y = __shfl_up(x_, off);
            if (lane >= off) x_ += y;
        }
        if (wd == 0 && lane == 63) ws0[0] = x_;
    }
    __syncthreads();
    if (tid < NBMAX) {
        int wo = wd ? ws0[0] : 0;
        lofs[tid] = wo + x_ - v_;
    }
    __syncthreads();

#pragma unroll
    for (int i = 0; i < EPT; ++i)
        if (bb[i] >= 0) buf[lofs[bb[i]] + rr[i]] = wv[i];
    if (tid < nb) gofs[tid] = lh[tid] ? atomicAdd(&bucket_cursor[tid], lh[tid]) : 0;
    __syncthreads();

    int wid = tid >> 6;
    for (int bk = wid; bk < nb; bk += 4) {
        int lo = lofs[bk], cnt = lh[bk], g = gofs[bk];
        for (int j = lane; j < cnt; j += 64)
            bucket_data[g + j] = buf[lo + j];
    }
}

__global__ __launch_bounds__(1024) void bucket_build_kernel(const int* __restrict__ bucket_base,
                                                            const unsigned* __restrict__ bucket_data,
                                                            int* __restrict__ deg,
                                                            int* __restrict__ row_start,
                                                            int* __restrict__ csr_src, int n) {
    __shared__ int lc[BKT];
    __shared__ int sc[BKT];
    __shared__ int wsum[16];

    int b = blockIdx.x;
    int base = bucket_base[b];
    int end  = bucket_base[b + 1];
    int t = threadIdx.x;

    lc[t] = 0;
    __syncthreads();
    for (int i = base + t; i < end; i += 1024)
        atomicAdd(&lc[bucket_data[i] >> 17], 1);
    __syncthreads();

    int val = lc[t];
    int lane = t & 63, wd = t >> 6;
    int x = val;
#pragma unroll
    for (int off = 1; off < 64; off <<= 1) {
        int y = __shfl_up(x, off);
        if (lane >= off) x += y;
    }
    if (lane == 63) wsum[wd] = x;
    __syncthreads();
    if (wd == 0 && lane < 16) {
        int y = wsum[lane];
#pragma unroll
        for (int off = 1; off < 16; off <<= 1) {
            int z = __shfl_up(y, off);
            if (lane >= off) y += z;
        }
        wsum[lane] = y;
    }
    __syncthreads();
    int wo = wd ? wsum[wd - 1] : 0;
    int excl = wo + x - val;
    sc[t] = excl;
    int v = b * BKT + t;
    if (v < n) { deg[v] = val; row_start[v] = base + excl; }
    lc[t] = 0;
    __syncthreads();

    for (int i = base + t; i < end; i += 1024) {
        unsigned w = bucket_data[i];
        int d = w >> 17;
        int src = (int)(w & 0x1FFFFu);
        int p = atomicAdd(&lc[d], 1);
        csr_src[base + sc[d] + p] = src;
    }
}

// ---------------- fused gather: single-pass softmax + weighted sum + bias + tanh ----
// one wave per dst node; lane owns channels {2*lane, 2*lane+1}; head = lane>>4.
// Every lane visits every edge: denominator accumulates per-lane (no reduce, no LDS).
__global__ __launch_bounds__(256) void gather_kernel(const int* __restrict__ row_start,
                                                     const int* __restrict__ deg,
                                                     const int* __restrict__ csr_src,
                                                     const float* __restrict__ alpha_s,
                                                     const float* __restrict__ alpha_d,
                                                     const unsigned short* __restrict__ h_bf,
                                                     const float* __restrict__ bias,
                                                     float* __restrict__ out, int n) {
    int lane = threadIdx.x & 63;
    int wid  = threadIdx.x >> 6;
    int v = blockIdx.x * 4 + wid;
    if (v >= n) return;
    int start = row_start[v];
    int cnt = deg[v];
    int head = lane >> 4;

    const unsigned* hb = reinterpret_cast<const unsigned*>(h_bf);

    float adH = alpha_d[(size_t)v * 4 + head];
    float asH = alpha_s[(size_t)v * 4 + head];
    float pself = __expf(lrelu(asH + adH));
    unsigned hv0 = hb[((unsigned)v << 6) + lane];
    float s = pself;
    float accx = pself * bf16_lo(hv0);
    float accy = pself * bf16_hi(hv0);

    int j = 0;
    for (; j + 8 <= cnt; j += 8) {
        int s0 = csr_src[start + j + 0];
        int s1 = csr_src[start + j + 1];
        int s2 = csr_src[start + j + 2];
        int s3 = csr_src[start + j + 3];
        int s4 = csr_src[start + j + 4];
        int s5 = csr_src[start + j + 5];
        int s6 = csr_src[start + j + 6];
        int s7 = csr_src[start + j + 7];
        float a0 = alpha_s[(size_t)s0 * 4 + head];
        float a1 = alpha_s[(size_t)s1 * 4 + head];
        float a2 = alpha_s[(size_t)s2 * 4 + head];
        float a3 = alpha_s[(size_t)s3 * 4 + head];
        float a4 = alpha_s[(size_t)s4 * 4 + head];
        float a5 = alpha_s[(size_t)s5 * 4 + head];
        float a6 = alpha_s[(size_t)s6 * 4 + head];
        float a7 = alpha_s[(size_t)s7 * 4 + head];
        unsigned h0 = hb[((unsigned)s0 << 6) + lane];
        unsigned h1 = hb[((unsigned)s1 << 6) + lane];
        unsigned h2 = hb[((unsigned)s2 << 6) + lane];
        unsigned h3 = hb[((unsigned)s3 << 6) + lane];
        unsigned h4 = hb[((unsigned)s4 << 6) + lane];
        unsigned h5 = hb[((unsigned)s5 << 6) + lane];
        unsigned h6 = hb[((unsigned)s6 << 6) + lane];
        unsigned h7 = hb[((unsigned)s7 << 6) + lane];
        float w0 = __expf(lrelu(a0 + adH));
        float w1 = __expf(lrelu(a1 + adH));
        float w2 = __expf(lrelu(a2 + adH));
        float w3 = __expf(lrelu(a3 + adH));
        float w4 = __expf(lrelu(a4 + adH));
        float w5 = __expf(lrelu(a5 + adH));
        float w6 = __expf(lrelu(a6 + adH));
        float w7 = __expf(lrelu(a7 + adH));
        s += w0 + w1 + w2 + w3 + w4 + w5 + w6 + w7;
        accx = fmaf(w0, bf16_lo(h0), accx); accy = fmaf(w0, bf16_hi(h0), accy);
        accx = fmaf(w1, bf16_lo(h1), accx); accy = fmaf(w1, bf16_hi(h1), accy);
        accx = fmaf(w2, bf16_lo(h2), accx); accy = fmaf(w2, bf16_hi(h2), accy);
        accx = fmaf(w3, bf16_lo(h3), accx); accy = fmaf(w3, bf16_hi(h3), accy);
        accx = fmaf(w4, bf16_lo(h4), accx); accy = fmaf(w4, bf16_hi(h4), accy);
        accx = fmaf(w5, bf16_lo(h5), accx); accy = fmaf(w5, bf16_hi(h5), accy);
        accx = fmaf(w6, bf16_lo(h6), accx); accy = fmaf(w6, bf16_hi(h6), accy);
        accx = fmaf(w7, bf16_lo(h7), accx); accy = fmaf(w7, bf16_hi(h7), accy);
    }
    for (; j + 4 <= cnt; j += 4) {
        int s0 = csr_src[start + j + 0];
        int s1 = csr_src[start + j + 1];
        int s2 = csr_src[start + j + 2];
        int s3 = csr_src[start + j + 3];
        float a0 = alpha_s[(size_t)s0 * 4 + head];
        float a1 = alpha_s[(size_t)s1 * 4 + head];
        float a2 = alpha_s[(size_t)s2 * 4 + head];
        float a3 = alpha_s[(size_t)s3 * 4 + head];
        unsigned h0 = hb[((unsigned)s0 << 6) + lane];
        unsigned h1 = hb[((unsigned)s1 << 6) + lane];
        unsigned h2 = hb[((unsigned)s2 << 6) + lane];
        unsigned h3 = hb[((unsigned)s3 << 6) + lane];
        float w0 = __expf(lrelu(a0 + adH));
        float w1 = __expf(lrelu(a1 + adH));
        float w2 = __expf(lrelu(a2 + adH));
        float w3 = __expf(lrelu(a3 + adH));
        s += w0 + w1 + w2 + w3;
        accx = fmaf(w0, bf16_lo(h0), accx); accy = fmaf(w0, bf16_hi(h0), accy);
        accx = fmaf(w1, bf16_lo(h1), accx); accy = fmaf(w1, bf16_hi(h1), accy);
        accx = fmaf(w2, bf16_lo(h2), accx); accy = fmaf(w2, bf16_hi(h2), accy);
        accx = fmaf(w3, bf16_lo(h3), accx); accy = fmaf(w3, bf16_hi(h3), accy);
    }
    for (; j < cnt; ++j) {
        int s0 = csr_src[start + j];
        float a0 = alpha_s[(size_t)s0 * 4 + head];
        unsigned h0 = hb[((unsigned)s0 << 6) + lane];
        float w0 = __expf(lrelu(a0 + adH));
        s += w0;
        accx = fmaf(w0, bf16_lo(h0), accx);
        accy = fmaf(w0, bf16_hi(h0), accy);
    }

    float invH = __builtin_amdgcn_rcpf(s + 1e-16f);
    float2 b = reinterpret_cast<const float2*>(bias)[lane];
    float2 o;
    o.x = fast_tanh(fmaf(accx, invH, b.x));
    o.y = fast_tanh(fmaf(accy, invH, b.y));
    reinterpret_cast<float2*>(out)[(size_t)v * 64 + lane] = o;
}

extern "C" void kernel_launch(void* const* d_in, const int* in_sizes, int n_in,
                              void* d_out, int out_size, void* d_ws, size_t ws_size,
                              hipStream_t stream) {
    const float* x     = (const float*)d_in[0];
    const float* W     = (const float*)d_in[1];
    const float* a_src = (const float*)d_in[2];
    const float* a_dst = (const float*)d_in[3];
    const float* bias  = (const float*)d_in[4];
    const int*   ei    = (const int*)d_in[5];

    const int n = in_sizes[0] / IN_DIM;        // 100000
    const int E = in_sizes[5] / 2;             // 1000000
    const int nb = (n + BKT - 1) / BKT;        // 98

    float* ws = (float*)d_ws;
    size_t off = 0;
    unsigned short* h_bf = (unsigned short*)(ws + off); off += (size_t)n * HC / 2;
    float* alpha_s = ws + off; off += (size_t)n * NHEAD;
    float* alpha_d = ws + off; off += (size_t)n * NHEAD;
    unsigned short* w_hi = (unsigned short*)(ws + off); off += 16384;
    int* ibase        = (int*)(ws + off);
    int* deg          = ibase;                        // n
    int* row_start    = ibase + n;                    // n
    int* bucket_cnt   = ibase + 2 * (size_t)n;        // NBMAX
    int* bucket_base  = bucket_cnt + NBMAX;           // NBMAX+1
    int* bucket_cursor= bucket_base + NBMAX + 1;      // NBMAX
    unsigned* bucket_data = (unsigned*)(bucket_cursor + NBMAX);  // E
    int* csr_src      = (int*)(bucket_data + E);      // E

    float* out = (float*)d_out;

    const int nblkE = (E + BE - 1) / BE;

    hipMemsetAsync(bucket_cnt, 0, NBMAX * sizeof(int), stream);

    pack_w_kernel<<<16, 256, 0, stream>>>(W, w_hi);
    gemm_mfma_kernel<<<(n + 63) / 64, 512, 0, stream>>>(x, w_hi, a_src, a_dst,
                                                        h_bf, alpha_s, alpha_d, n);

    bucket_hist_kernel<<<nblkE, 256, 0, stream>>>(ei, bucket_cnt, E, nb);
    bucket_scan_kernel<<<1, 128, 0, stream>>>(bucket_cnt, bucket_base, bucket_cursor, nb);
    bucket_scatter_kernel<<<nblkE, 256, 0, stream>>>(ei, bucket_cursor, bucket_data, E, nb);
    bucket_build_kernel<<<nb, 1024, 0, stream>>>(bucket_base, bucket_data,
                                                 deg, row_start, csr_src, n);

    gather_kernel<<<(n + 3) / 4, 256, 0, stream>>>(row_start, deg, csr_src,
                                                   alpha_s, alpha_d, h_bf, bias, out, n);
}

// Round 10
// 146.455 us; speedup vs baseline: 1.0935x; 1.0469x over previous
//
#include <hip/hip_runtime.h>

#define IN_DIM 256
#define HC     128   // H*C
#define NHEAD  4
#define NEG    0.2f
#define BKT    1024  // dsts per bucket
#define NBMAX  128   // max buckets (n <= 131072)
#define EPT    16    // edges per thread (bucket hist/scatter)
#define BE     4096  // edges per block = 256*EPT

typedef __attribute__((ext_vector_type(8))) short short8v;
typedef __attribute__((ext_vector_type(4))) float f32x4;
typedef __attribute__((ext_vector_type(4))) unsigned short ushort4v;

__device__ __forceinline__ unsigned short bf16_rn(float f) {
    unsigned u = __builtin_bit_cast(unsigned, f);
    return (unsigned short)((u + 0x7fffu + ((u >> 16) & 1u)) >> 16);
}
__device__ __forceinline__ float bf16_to_f32(unsigned short b) {
    unsigned u = ((unsigned)b) << 16;
    return __builtin_bit_cast(float, u);
}
__device__ __forceinline__ float bf16_lo(unsigned v) {
    return __builtin_bit_cast(float, v << 16);
}
__device__ __forceinline__ float bf16_hi(unsigned v) {
    return __builtin_bit_cast(float, v & 0xffff0000u);
}
__device__ __forceinline__ float fast_tanh(float x) {
    float t = __expf(2.f * x);
    return fmaf(-2.f, __builtin_amdgcn_rcpf(t + 1.f), 1.f);
}
__device__ __forceinline__ float lrelu(float e) {
    return fmaxf(e, NEG * e);
}

// ---------------- pack W (hi bf16) into MFMA fragment order ----------------
__global__ void pack_w_kernel(const float* __restrict__ W,
                              unsigned short* __restrict__ w_hi) {
    int t = blockIdx.x * 256 + threadIdx.x;
    if (t >= 8 * 8 * 64) return;
    int l  = t & 63;
    int ct = (t >> 6) & 7;
    int s  = t >> 9;
    int kbase = s * 32 + (l >> 4) * 8;
    int col   = ct * 16 + (l & 15);
    size_t base = (size_t)t * 8;
#pragma unroll
    for (int e = 0; e < 8; ++e)
        w_hi[base + e] = bf16_rn(W[(size_t)(kbase + e) * HC + col]);
}

// ---------------- GEMM: h = x @ W via bf16 MFMA ----------------
// x staged as bf16 in XOR-swizzled LDS (32 KB). 512 threads = 8 waves.
// Wave wv: ct_g = wv&3 (32 cols = head), rt_g = wv>>2 (32 rows); 2x2 16x16 tiles.
__global__ __launch_bounds__(512) void gemm_mfma_kernel(const float* __restrict__ x,
                                                        const unsigned short* __restrict__ w_hi,
                                                        const float* __restrict__ a_src,
                                                        const float* __restrict__ a_dst,
                                                        unsigned short* __restrict__ h_bf,
                                                        float* __restrict__ alpha_s,
                                                        float* __restrict__ alpha_d, int n) {
    __shared__ unsigned short s_bf[64 * 256];   // 32 KB, swizzled 16B slots
    __shared__ float pS[64][4];
    __shared__ float pD[64][4];

    const int tid = threadIdx.x;
    const int l   = tid & 63;
    const int wv  = tid >> 6;
    const int row0 = blockIdx.x * 64;

    // ---- stage + convert: 64 rows x 256 cols bf16 -> swizzled LDS
    // iteration i: wave wv writes row i*8+wv; lane l writes float4 c4=l.
    const float4* x4 = reinterpret_cast<const float4*>(x);
#pragma unroll
    for (int i = 0; i < 8; ++i) {
        int row = i * 8 + wv;
        int c4  = l;
        float4 v = make_float4(0.f, 0.f, 0.f, 0.f);
        if (row0 + row < n) v = x4[(size_t)(row0 + row) * 64 + c4];
        ushort4v b;
        b[0] = bf16_rn(v.x); b[1] = bf16_rn(v.y);
        b[2] = bf16_rn(v.z); b[3] = bf16_rn(v.w);
        int slot = (c4 >> 1) ^ (row & 7);                 // 16B-slot swizzle
        int uidx = row * 256 + (slot << 3) + ((c4 & 1) << 2);
        *reinterpret_cast<ushort4v*>(&s_bf[uidx]) = b;
    }
    __syncthreads();

    const int ct_g = wv & 3;
    const int rt_g = wv >> 2;
    const int rrow = l & 15;
    const int kq   = l >> 4;          // 0..3 -> c16 contribution

    f32x4 acc[2][2];
#pragma unroll
    for (int a = 0; a < 2; ++a)
#pragma unroll
        for (int b = 0; b < 2; ++b) acc[a][b] = (f32x4){0.f, 0.f, 0.f, 0.f};

    for (int s = 0; s < 8; ++s) {
        short8v bh[2];
#pragma unroll
        for (int c = 0; c < 2; ++c) {
            int ct = ct_g * 2 + c;
            bh[c] = *reinterpret_cast<const short8v*>(w_hi + ((size_t)(s * 8 + ct) * 64 + l) * 8);
        }
#pragma unroll
        for (int r = 0; r < 2; ++r) {
            int arow = rt_g * 32 + r * 16 + rrow;
            int c16  = kq + s * 4;                        // 16B slot (logical)
            int uidx = arow * 256 + ((c16 ^ (arow & 7)) << 3);
            short8v ah = *reinterpret_cast<const short8v*>(&s_bf[uidx]);
#pragma unroll
            for (int c = 0; c < 2; ++c)
                acc[r][c] = __builtin_amdgcn_mfma_f32_16x16x32_bf16(ah, bh[c], acc[r][c], 0, 0, 0);
        }
    }

    // ---- epilogue 1: h as bf16. C layout: col = lane&15, row = (lane>>4)*4 + reg
#pragma unroll
    for (int r = 0; r < 2; ++r) {
#pragma unroll
        for (int c = 0; c < 2; ++c) {
            int col = (ct_g * 2 + c) * 16 + (l & 15);
#pragma unroll
            for (int q = 0; q < 4; ++q) {
                int row = row0 + rt_g * 32 + r * 16 + (l >> 4) * 4 + q;
                if (row < n) h_bf[(size_t)row * HC + col] = bf16_rn(acc[r][c][q]);
            }
        }
    }

    // ---- epilogue 2: alpha logits (wave's 32 cols == head ct_g)
    float asc[2], adc[2];
#pragma unroll
    for (int c = 0; c < 2; ++c) {
        int col = (ct_g * 2 + c) * 16 + (l & 15);
        asc[c] = a_src[col];
        adc[c] = a_dst[col];
    }
#pragma unroll
    for (int r = 0; r < 2; ++r) {
#pragma unroll
        for (int q = 0; q < 4; ++q) {
            float vS = acc[r][0][q] * asc[0] + acc[r][1][q] * asc[1];
            float vD = acc[r][0][q] * adc[0] + acc[r][1][q] * adc[1];
#pragma unroll
            for (int m = 1; m < 16; m <<= 1) {
                vS += __shfl_xor(vS, m);
                vD += __shfl_xor(vD, m);
            }
            if ((l & 15) == 0) {
                int rl = rt_g * 32 + r * 16 + (l >> 4) * 4 + q;
                pS[rl][ct_g] = vS;
                pD[rl][ct_g] = vD;
            }
        }
    }
    __syncthreads();
    if (tid < 256) {
        int rl = tid >> 2, h = tid & 3;
        int row = row0 + rl;
        if (row < n) {
            alpha_s[(size_t)row * 4 + h] = pS[rl][h];
            alpha_d[(size_t)row * 4 + h] = pD[rl][h];
        }
    }
}

// ---------------- CSR build: two-level counting sort by dst ----------------
__global__ __launch_bounds__(256) void bucket_hist_kernel(const int* __restrict__ ei,
                                                          int* __restrict__ bucket_cnt,
                                                          int E, int nb) {
    __shared__ int lh[NBMAX];
    int tid = threadIdx.x;
    if (tid < NBMAX) lh[tid] = 0;
    __syncthreads();
    int base = blockIdx.x * BE;
#pragma unroll
    for (int i = 0; i < EPT; ++i) {
        int e = base + i * 256 + tid;
        if (e < E) atomicAdd(&lh[ei[E + e] >> 10], 1);
    }
    __syncthreads();
    if (tid < nb && lh[tid]) atomicAdd(&bucket_cnt[tid], lh[tid]);
}

__global__ __launch_bounds__(128) void bucket_scan_kernel(const int* __restrict__ bucket_cnt,
                                                          int* __restrict__ bucket_base,
                                                          int* __restrict__ bucket_cursor,
                                                          int nb) {
    __shared__ int ws0[1];
    int t = threadIdx.x;
    int v = (t < nb) ? bucket_cnt[t] : 0;
    int lane = t & 63, wd = t >> 6;
    int x = v;
#pragma unroll
    for (int off = 1; off < 64; off <<= 1) {
        int y = __shfl_up(x, off);
        if (lane >= off) x += y;
    }
    if (wd == 0 && lane == 63) ws0[0] = x;
    __syncthreads();
    int wo = wd ? ws0[0] : 0;
    int excl = wo + x - v;
    if (t < nb) { bucket_base[t] = excl; bucket_cursor[t] = excl; }
    if (t == 127) bucket_base[nb] = wo + x;   // total = E
}

__global__ __launch_bounds__(256) void bucket_scatter_kernel(const int* __restrict__ ei,
                                                             int* __restrict__ bucket_cursor,
                                                             unsigned* __restrict__ bucket_data,
                                                             int E, int nb) {
    __shared__ int lh[NBMAX];
    __shared__ int lofs[NBMAX];
    __shared__ int gofs[NBMAX];
    __shared__ int ws0[1];
    __shared__ unsigned buf[BE];

    int tid = threadIdx.x;
    if (tid < NBMAX) lh[tid] = 0;
    __syncthreads();

    int base = blockIdx.x * BE;
    int bb[EPT]; unsigned wv[EPT]; int rr[EPT];
#pragma unroll
    for (int i = 0; i < EPT; ++i) {
        int e = base + i * 256 + tid;
        if (e < E) {
            int src = ei[e];
            int dst = ei[E + e];
            bb[i] = dst >> 10;
            wv[i] = (unsigned)src | ((unsigned)(dst & 1023) << 17);
            rr[i] = atomicAdd(&lh[bb[i]], 1);
        } else bb[i] = -1;
    }
    __syncthreads();

    int v_ = 0, x_ = 0;
    int lane = tid & 63, wd = tid >> 6;
    if (tid < NBMAX) {
        v_ = lh[tid]; x_ = v_;
#pragma unroll
        for (int off = 1; off < 64; off <<= 1) {
            int y = __shfl_up(x_, off);
            if (lane >= off) x_ += y;
        }
        if (wd == 0 && lane == 63) ws0[0] = x_;
    }
    __syncthreads();
    if (tid < NBMAX) {
        int wo = wd ? ws0[0] : 0;
        lofs[tid] = wo + x_ - v_;
    }
    __syncthreads();

#pragma unroll
    for (int i = 0; i < EPT; ++i)
        if (bb[i] >= 0) buf[lofs[bb[i]] + rr[i]] = wv[i];
    if (tid < nb) gofs[tid] = lh[tid] ? atomicAdd(&bucket_cursor[tid], lh[tid]) : 0;
    __syncthreads();

    int wid = tid >> 6;
    for (int bk = wid; bk < nb; bk += 4) {
        int lo = lofs[bk], cnt = lh[bk], g = gofs[bk];
        for (int j = lane; j < cnt; j += 64)
            bucket_data[g + j] = buf[lo + j];
    }
}

__global__ __launch_bounds__(1024) void bucket_build_kernel(const int* __restrict__ bucket_base,
                                                            const unsigned* __restrict__ bucket_data,
                                                            int* __restrict__ deg,
                                                            int* __restrict__ row_start,
                                                            int* __restrict__ csr_src, int n) {
    __shared__ int lc[BKT];
    __shared__ int sc[BKT];
    __shared__ int wsum[16];

    int b = blockIdx.x;
    int base = bucket_base[b];
    int end  = bucket_base[b + 1];
    int t = threadIdx.x;

    lc[t] = 0;
    __syncthreads();
    for (int i = base + t; i < end; i += 1024)
        atomicAdd(&lc[bucket_data[i] >> 17], 1);
    __syncthreads();

    int val = lc[t];
    int lane = t & 63, wd = t >> 6;
    int x = val;
#pragma unroll
    for (int off = 1; off < 64; off <<= 1) {
        int y = __shfl_up(x, off);
        if (lane >= off) x += y;
    }
    if (lane == 63) wsum[wd] = x;
    __syncthreads();
    if (wd == 0 && lane < 16) {
        int y = wsum[lane];
#pragma unroll
        for (int off = 1; off < 16; off <<= 1) {
            int z = __shfl_up(y, off);
            if (lane >= off) y += z;
        }
        wsum[lane] = y;
    }
    __syncthreads();
    int wo = wd ? wsum[wd - 1] : 0;
    int excl = wo + x - val;
    sc[t] = excl;
    int v = b * BKT + t;
    if (v < n) { deg[v] = val; row_start[v] = base + excl; }
    lc[t] = 0;
    __syncthreads();

    for (int i = base + t; i < end; i += 1024) {
        unsigned w = bucket_data[i];
        int d = w >> 17;
        int src = (int)(w & 0x1FFFFu);
        int p = atomicAdd(&lc[d], 1);
        csr_src[base + sc[d] + p] = src;
    }
}

// ---------------- fused gather: single-pass softmax + weighted sum + bias + tanh ----
__global__ __launch_bounds__(256) void gather_kernel(const int* __restrict__ row_start,
                                                     const int* __restrict__ deg,
                                                     const int* __restrict__ csr_src,
                                                     const float* __restrict__ alpha_s,
                                                     const float* __restrict__ alpha_d,
                                                     const unsigned short* __restrict__ h_bf,
                                                     const float* __restrict__ bias,
                                                     float* __restrict__ out, int n) {
    int lane = threadIdx.x & 63;
    int wid  = threadIdx.x >> 6;
    int v = blockIdx.x * 4 + wid;
    if (v >= n) return;
    int start = row_start[v];
    int cnt = deg[v];
    int head = lane >> 4;

    const unsigned* hb = reinterpret_cast<const unsigned*>(h_bf);

    float adH = alpha_d[(size_t)v * 4 + head];
    float asH = alpha_s[(size_t)v * 4 + head];
    float pself = __expf(lrelu(asH + adH));
    unsigned hv0 = hb[((unsigned)v << 6) + lane];
    float s = pself;
    float accx = pself * bf16_lo(hv0);
    float accy = pself * bf16_hi(hv0);

    int j = 0;
    for (; j + 8 <= cnt; j += 8) {
        int s0 = csr_src[start + j + 0];
        int s1 = csr_src[start + j + 1];
        int s2 = csr_src[start + j + 2];
        int s3 = csr_src[start + j + 3];
        int s4 = csr_src[start + j + 4];
        int s5 = csr_src[start + j + 5];
        int s6 = csr_src[start + j + 6];
        int s7 = csr_src[start + j + 7];
        float a0 = alpha_s[(size_t)s0 * 4 + head];
        float a1 = alpha_s[(size_t)s1 * 4 + head];
        float a2 = alpha_s[(size_t)s2 * 4 + head];
        float a3 = alpha_s[(size_t)s3 * 4 + head];
        float a4 = alpha_s[(size_t)s4 * 4 + head];
        float a5 = alpha_s[(size_t)s5 * 4 + head];
        float a6 = alpha_s[(size_t)s6 * 4 + head];
        float a7 = alpha_s[(size_t)s7 * 4 + head];
        unsigned h0 = hb[((unsigned)s0 << 6) + lane];
        unsigned h1 = hb[((unsigned)s1 << 6) + lane];
        unsigned h2 = hb[((unsigned)s2 << 6) + lane];
        unsigned h3 = hb[((unsigned)s3 << 6) + lane];
        unsigned h4 = hb[((unsigned)s4 << 6) + lane];
        unsigned h5 = hb[((unsigned)s5 << 6) + lane];
        unsigned h6 = hb[((unsigned)s6 << 6) + lane];
        unsigned h7 = hb[((unsigned)s7 << 6) + lane];
        float w0 = __expf(lrelu(a0 + adH));
        float w1 = __expf(lrelu(a1 + adH));
        float w2 = __expf(lrelu(a2 + adH));
        float w3 = __expf(lrelu(a3 + adH));
        float w4 = __expf(lrelu(a4 + adH));
        float w5 = __expf(lrelu(a5 + adH));
        float w6 = __expf(lrelu(a6 + adH));
        float w7 = __expf(lrelu(a7 + adH));
        s += w0 + w1 + w2 + w3 + w4 + w5 + w6 + w7;
        accx = fmaf(w0, bf16_lo(h0), accx); accy = fmaf(w0, bf16_hi(h0), accy);
        accx = fmaf(w1, bf16_lo(h1), accx); accy = fmaf(w1, bf16_hi(h1), accy);
        accx = fmaf(w2, bf16_lo(h2), accx); accy = fmaf(w2, bf16_hi(h2), accy);
        accx = fmaf(w3, bf16_lo(h3), accx); accy = fmaf(w3, bf16_hi(h3), accy);
        accx = fmaf(w4, bf16_lo(h4), accx); accy = fmaf(w4, bf16_hi(h4), accy);
        accx = fmaf(w5, bf16_lo(h5), accx); accy = fmaf(w5, bf16_hi(h5), accy);
        accx = fmaf(w6, bf16_lo(h6), accx); accy = fmaf(w6, bf16_hi(h6), accy);
        accx = fmaf(w7, bf16_lo(h7), accx); accy = fmaf(w7, bf16_hi(h7), accy);
    }
    for (; j + 4 <= cnt; j += 4) {
        int s0 = csr_src[start + j + 0];
        int s1 = csr_src[start + j + 1];
        int s2 = csr_src[start + j + 2];
        int s3 = csr_src[start + j + 3];
        float a0 = alpha_s[(size_t)s0 * 4 + head];
        float a1 = alpha_s[(size_t)s1 * 4 + head];
        float a2 = alpha_s[(size_t)s2 * 4 + head];
        float a3 = alpha_s[(size_t)s3 * 4 + head];
        unsigned h0 = hb[((unsigned)s0 << 6) + lane];
        unsigned h1 = hb[((unsigned)s1 << 6) + lane];
        unsigned h2 = hb[((unsigned)s2 << 6) + lane];
        unsigned h3 = hb[((unsigned)s3 << 6) + lane];
        float w0 = __expf(lrelu(a0 + adH));
        float w1 = __expf(lrelu(a1 + adH));
        float w2 = __expf(lrelu(a2 + adH));
        float w3 = __expf(lrelu(a3 + adH));
        s += w0 + w1 + w2 + w3;
        accx = fmaf(w0, bf16_lo(h0), accx); accy = fmaf(w0, bf16_hi(h0), accy);
        accx = fmaf(w1, bf16_lo(h1), accx); accy = fmaf(w1, bf16_hi(h1), accy);
        accx = fmaf(w2, bf16_lo(h2), accx); accy = fmaf(w2, bf16_hi(h2), accy);
        accx = fmaf(w3, bf16_lo(h3), accx); accy = fmaf(w3, bf16_hi(h3), accy);
    }
    for (; j < cnt; ++j) {
        int s0 = csr_src[start + j];
        float a0 = alpha_s[(size_t)s0 * 4 + head];
        unsigned h0 = hb[((unsigned)s0 << 6) + lane];
        float w0 = __expf(lrelu(a0 + adH));
        s += w0;
        accx = fmaf(w0, bf16_lo(h0), accx);
        accy = fmaf(w0, bf16_hi(h0), accy);
    }

    float invH = __builtin_amdgcn_rcpf(s + 1e-16f);
    float2 b = reinterpret_cast<const float2*>(bias)[lane];
    float2 o;
    o.x = fast_tanh(fmaf(accx, invH, b.x));
    o.y = fast_tanh(fmaf(accy, invH, b.y));
    reinterpret_cast<float2*>(out)[(size_t)v * 64 + lane] = o;
}

extern "C" void kernel_launch(void* const* d_in, const int* in_sizes, int n_in,
                              void* d_out, int out_size, void* d_ws, size_t ws_size,
                              hipStream_t stream) {
    const float* x     = (const float*)d_in[0];
    const float* W     = (const float*)d_in[1];
    const float* a_src = (const float*)d_in[2];
    const float* a_dst = (const float*)d_in[3];
    const float* bias  = (const float*)d_in[4];
    const int*   ei    = (const int*)d_in[5];

    const int n = in_sizes[0] / IN_DIM;        // 100000
    const int E = in_sizes[5] / 2;             // 1000000
    const int nb = (n + BKT - 1) / BKT;        // 98

    float* ws = (float*)d_ws;
    size_t off = 0;
    unsigned short* h_bf = (unsigned short*)(ws + off); off += (size_t)n * HC / 2;
    float* alpha_s = ws + off; off += (size_t)n * NHEAD;
    float* alpha_d = ws + off; off += (size_t)n * NHEAD;
    unsigned short* w_hi = (unsigned short*)(ws + off); off += 16384;
    int* ibase        = (int*)(ws + off);
    int* deg          = ibase;                        // n
    int* row_start    = ibase + n;                    // n
    int* bucket_cnt   = ibase + 2 * (size_t)n;        // NBMAX
    int* bucket_base  = bucket_cnt + NBMAX;           // NBMAX+1
    int* bucket_cursor= bucket_base + NBMAX + 1;      // NBMAX
    unsigned* bucket_data = (unsigned*)(bucket_cursor + NBMAX);  // E
    int* csr_src      = (int*)(bucket_data + E);      // E

    float* out = (float*)d_out;

    const int nblkE = (E + BE - 1) / BE;

    hipMemsetAsync(bucket_cnt, 0, NBMAX * sizeof(int), stream);

    pack_w_kernel<<<16, 256, 0, stream>>>(W, w_hi);
    gemm_mfma_kernel<<<(n + 63) / 64, 512, 0, stream>>>(x, w_hi, a_src, a_dst,
                                                        h_bf, alpha_s, alpha_d, n);

    bucket_hist_kernel<<<nblkE, 256, 0, stream>>>(ei, bucket_cnt, E, nb);
    bucket_scan_kernel<<<1, 128, 0, stream>>>(bucket_cnt, bucket_base, bucket_cursor, nb);
    bucket_scatter_kernel<<<nblkE, 256, 0, stream>>>(ei, bucket_cursor, bucket_data, E, nb);
    bucket_build_kernel<<<nb, 1024, 0, stream>>>(bucket_base, bucket_data,
                                                 deg, row_start, csr_src, n);

    gather_kernel<<<(n + 3) / 4, 256, 0, stream>>>(row_start, deg, csr_src,
                                                   alpha_s, alpha_d, h_bf, bias, out, n);
}

// Round 11
// 133.703 us; speedup vs baseline: 1.1977x; 1.0954x over previous
//
#include <hip/hip_runtime.h>

#define IN_DIM 256
#define HC     128   // H*C
#define NHEAD  4
#define NEG    0.2f
#define BKT    1024  // dsts per bucket
#define NBMAX  128   // max buckets (n <= 131072)
#define EPT2   8     // edges per thread (fused 512-thr scatter)
#define BE     4096  // edges per block
#define PACKB  16    // pack_w blocks in fused K1

typedef __attribute__((ext_vector_type(8))) short short8v;
typedef __attribute__((ext_vector_type(4))) float f32x4;
typedef __attribute__((ext_vector_type(4))) unsigned short ushort4v;

__device__ __forceinline__ unsigned short bf16_rn(float f) {
    unsigned u = __builtin_bit_cast(unsigned, f);
    return (unsigned short)((u + 0x7fffu + ((u >> 16) & 1u)) >> 16);
}
__device__ __forceinline__ float bf16_lo(unsigned v) {
    return __builtin_bit_cast(float, v << 16);
}
__device__ __forceinline__ float bf16_hi(unsigned v) {
    return __builtin_bit_cast(float, v & 0xffff0000u);
}
__device__ __forceinline__ float fast_tanh(float x) {
    float t = __expf(2.f * x);
    return fmaf(-2.f, __builtin_amdgcn_rcpf(t + 1.f), 1.f);
}
__device__ __forceinline__ float lrelu(float e) {
    return fmaxf(e, NEG * e);
}

// ---------------- K1: pack W (blocks 0..15)  ||  bucket histogram (rest) ----------------
__global__ __launch_bounds__(256) void pack_hist_kernel(const float* __restrict__ W,
                                                        unsigned short* __restrict__ w_hi,
                                                        const int* __restrict__ ei,
                                                        int* __restrict__ bucket_cnt,
                                                        int E, int nb) {
    __shared__ int lh[NBMAX];
    int tid = threadIdx.x;
    if (blockIdx.x < PACKB) {
        // pack W (hi bf16) into MFMA fragment order
        int t = blockIdx.x * 256 + tid;
        int l  = t & 63;
        int ct = (t >> 6) & 7;
        int s  = t >> 9;
        int kbase = s * 32 + (l >> 4) * 8;
        int col   = ct * 16 + (l & 15);
        size_t base = (size_t)t * 8;
#pragma unroll
        for (int e = 0; e < 8; ++e)
            w_hi[base + e] = bf16_rn(W[(size_t)(kbase + e) * HC + col]);
        return;
    }
    // histogram path
    if (tid < NBMAX) lh[tid] = 0;
    __syncthreads();
    int base = (blockIdx.x - PACKB) * BE;
#pragma unroll
    for (int i = 0; i < 16; ++i) {
        int e = base + i * 256 + tid;
        if (e < E) atomicAdd(&lh[ei[E + e] >> 10], 1);
    }
    __syncthreads();
    if (tid < nb && lh[tid]) atomicAdd(&bucket_cnt[tid], lh[tid]);
}

// ---------------- K2: exclusive scan of bucket counts ----------------
__global__ __launch_bounds__(128) void bucket_scan_kernel(const int* __restrict__ bucket_cnt,
                                                          int* __restrict__ bucket_base,
                                                          int* __restrict__ bucket_cursor,
                                                          int nb) {
    __shared__ int ws0[1];
    int t = threadIdx.x;
    int v = (t < nb) ? bucket_cnt[t] : 0;
    int lane = t & 63, wd = t >> 6;
    int x = v;
#pragma unroll
    for (int off = 1; off < 64; off <<= 1) {
        int y = __shfl_up(x, off);
        if (lane >= off) x += y;
    }
    if (wd == 0 && lane == 63) ws0[0] = x;
    __syncthreads();
    int wo = wd ? ws0[0] : 0;
    int excl = wo + x - v;
    if (t < nb) { bucket_base[t] = excl; bucket_cursor[t] = excl; }
    if (t == 127) bucket_base[nb] = wo + x;   // total = E
}

// ---------------- K3: bucket scatter (blocks 0..nblkE-1)  ||  GEMM (rest) -------------
union KSmem {
    struct {
        unsigned short s_bf[64 * 256];   // 32 KB swizzled A tile
        float pS[64][4];
        float pD[64][4];
    } g;
    struct {
        int lh[NBMAX];
        int lofs[NBMAX];
        int gofs[NBMAX];
        int ws0;
        unsigned buf[BE];                // 16 KB
    } s;
};

__global__ __launch_bounds__(512) void scatter_gemm_kernel(const int* __restrict__ ei,
                                                           int* __restrict__ bucket_cursor,
                                                           unsigned* __restrict__ bucket_data,
                                                           int E, int nb, int nblkE,
                                                           const float* __restrict__ x,
                                                           const unsigned short* __restrict__ w_hi,
                                                           const float* __restrict__ a_src,
                                                           const float* __restrict__ a_dst,
                                                           unsigned short* __restrict__ h_bf,
                                                           float* __restrict__ alpha_s,
                                                           float* __restrict__ alpha_d, int n) {
    __shared__ KSmem sm;
    const int tid = threadIdx.x;

    if ((int)blockIdx.x < nblkE) {
        // ---------------- scatter path (512 threads, EPT2=8) ----------------
        if (tid < NBMAX) sm.s.lh[tid] = 0;
        __syncthreads();

        int base = blockIdx.x * BE;
        int bb[EPT2]; unsigned wv[EPT2]; int rr[EPT2];
#pragma unroll
        for (int i = 0; i < EPT2; ++i) {
            int e = base + i * 512 + tid;
            if (e < E) {
                int src = ei[e];
                int dst = ei[E + e];
                bb[i] = dst >> 10;
                wv[i] = (unsigned)src | ((unsigned)(dst & 1023) << 17);
                rr[i] = atomicAdd(&sm.s.lh[bb[i]], 1);
            } else bb[i] = -1;
        }
        __syncthreads();

        // scan lh -> lofs (first 128 threads)
        int lane = tid & 63, wd = tid >> 6;
        int v_ = 0, x_ = 0;
        if (tid < NBMAX) {
            v_ = sm.s.lh[tid]; x_ = v_;
#pragma unroll
            for (int off = 1; off < 64; off <<= 1) {
                int y = __shfl_up(x_, off);
                if (lane >= off) x_ += y;
            }
            if (wd == 0 && lane == 63) sm.s.ws0 = x_;
        }
        __syncthreads();
        if (tid < NBMAX) {
            int wo = wd ? sm.s.ws0 : 0;
            sm.s.lofs[tid] = wo + x_ - v_;
        }
        __syncthreads();

#pragma unroll
        for (int i = 0; i < EPT2; ++i)
            if (bb[i] >= 0) sm.s.buf[sm.s.lofs[bb[i]] + rr[i]] = wv[i];
        if (tid < nb) sm.s.gofs[tid] = sm.s.lh[tid] ? atomicAdd(&bucket_cursor[tid], sm.s.lh[tid]) : 0;
        __syncthreads();

        int wid = tid >> 6;   // 8 waves
        for (int bk = wid; bk < nb; bk += 8) {
            int lo = sm.s.lofs[bk], cnt = sm.s.lh[bk], g = sm.s.gofs[bk];
            for (int j = lane; j < cnt; j += 64)
                bucket_data[g + j] = sm.s.buf[lo + j];
        }
        return;
    }

    // ---------------- GEMM path ----------------
    const int l   = tid & 63;
    const int wv_ = tid >> 6;
    const int row0 = ((int)blockIdx.x - nblkE) * 64;

    const float4* x4 = reinterpret_cast<const float4*>(x);
#pragma unroll
    for (int i = 0; i < 8; ++i) {
        int row = i * 8 + wv_;
        int c4  = l;
        float4 v = make_float4(0.f, 0.f, 0.f, 0.f);
        if (row0 + row < n) v = x4[(size_t)(row0 + row) * 64 + c4];
        ushort4v b;
        b[0] = bf16_rn(v.x); b[1] = bf16_rn(v.y);
        b[2] = bf16_rn(v.z); b[3] = bf16_rn(v.w);
        int slot = (c4 >> 1) ^ (row & 7);
        int uidx = row * 256 + (slot << 3) + ((c4 & 1) << 2);
        *reinterpret_cast<ushort4v*>(&sm.g.s_bf[uidx]) = b;
    }
    __syncthreads();

    const int ct_g = wv_ & 3;
    const int rt_g = wv_ >> 2;
    const int rrow = l & 15;
    const int kq   = l >> 4;

    f32x4 acc[2][2];
#pragma unroll
    for (int a = 0; a < 2; ++a)
#pragma unroll
        for (int b = 0; b < 2; ++b) acc[a][b] = (f32x4){0.f, 0.f, 0.f, 0.f};

    for (int s = 0; s < 8; ++s) {
        short8v bh[2];
#pragma unroll
        for (int c = 0; c < 2; ++c) {
            int ct = ct_g * 2 + c;
            bh[c] = *reinterpret_cast<const short8v*>(w_hi + ((size_t)(s * 8 + ct) * 64 + l) * 8);
        }
#pragma unroll
        for (int r = 0; r < 2; ++r) {
            int arow = rt_g * 32 + r * 16 + rrow;
            int c16  = kq + s * 4;
            int uidx = arow * 256 + ((c16 ^ (arow & 7)) << 3);
            short8v ah = *reinterpret_cast<const short8v*>(&sm.g.s_bf[uidx]);
#pragma unroll
            for (int c = 0; c < 2; ++c)
                acc[r][c] = __builtin_amdgcn_mfma_f32_16x16x32_bf16(ah, bh[c], acc[r][c], 0, 0, 0);
        }
    }

#pragma unroll
    for (int r = 0; r < 2; ++r) {
#pragma unroll
        for (int c = 0; c < 2; ++c) {
            int col = (ct_g * 2 + c) * 16 + (l & 15);
#pragma unroll
            for (int q = 0; q < 4; ++q) {
                int row = row0 + rt_g * 32 + r * 16 + (l >> 4) * 4 + q;
                if (row < n) h_bf[(size_t)row * HC + col] = bf16_rn(acc[r][c][q]);
            }
        }
    }

    float asc[2], adc[2];
#pragma unroll
    for (int c = 0; c < 2; ++c) {
        int col = (ct_g * 2 + c) * 16 + (l & 15);
        asc[c] = a_src[col];
        adc[c] = a_dst[col];
    }
#pragma unroll
    for (int r = 0; r < 2; ++r) {
#pragma unroll
        for (int q = 0; q < 4; ++q) {
            float vS = acc[r][0][q] * asc[0] + acc[r][1][q] * asc[1];
            float vD = acc[r][0][q] * adc[0] + acc[r][1][q] * adc[1];
#pragma unroll
            for (int m = 1; m < 16; m <<= 1) {
                vS += __shfl_xor(vS, m);
                vD += __shfl_xor(vD, m);
            }
            if ((l & 15) == 0) {
                int rl = rt_g * 32 + r * 16 + (l >> 4) * 4 + q;
                sm.g.pS[rl][ct_g] = vS;
                sm.g.pD[rl][ct_g] = vD;
            }
        }
    }
    __syncthreads();
    if (tid < 256) {
        int rl = tid >> 2, h = tid & 3;
        int row = row0 + rl;
        if (row < n) {
            alpha_s[(size_t)row * 4 + h] = sm.g.pS[rl][h];
            alpha_d[(size_t)row * 4 + h] = sm.g.pD[rl][h];
        }
    }
}

// ---------------- K4: per-bucket CSR finalize (LDS atomics only) ----------------
__global__ __launch_bounds__(1024) void bucket_build_kernel(const int* __restrict__ bucket_base,
                                                            const unsigned* __restrict__ bucket_data,
                                                            int* __restrict__ deg,
                                                            int* __restrict__ row_start,
                                                            int* __restrict__ csr_src, int n) {
    __shared__ int lc[BKT];
    __shared__ int sc[BKT];
    __shared__ int wsum[16];

    int b = blockIdx.x;
    int base = bucket_base[b];
    int end  = bucket_base[b + 1];
    int t = threadIdx.x;

    lc[t] = 0;
    __syncthreads();
    for (int i = base + t; i < end; i += 1024)
        atomicAdd(&lc[bucket_data[i] >> 17], 1);
    __syncthreads();

    int val = lc[t];
    int lane = t & 63, wd = t >> 6;
    int x = val;
#pragma unroll
    for (int off = 1; off < 64; off <<= 1) {
        int y = __shfl_up(x, off);
        if (lane >= off) x += y;
    }
    if (lane == 63) wsum[wd] = x;
    __syncthreads();
    if (wd == 0 && lane < 16) {
        int y = wsum[lane];
#pragma unroll
        for (int off = 1; off < 16; off <<= 1) {
            int z = __shfl_up(y, off);
            if (lane >= off) y += z;
        }
        wsum[lane] = y;
    }
    __syncthreads();
    int wo = wd ? wsum[wd - 1] : 0;
    int excl = wo + x - val;
    sc[t] = excl;
    int v = b * BKT + t;
    if (v < n) { deg[v] = val; row_start[v] = base + excl; }
    lc[t] = 0;
    __syncthreads();

    for (int i = base + t; i < end; i += 1024) {
        unsigned w = bucket_data[i];
        int d = w >> 17;
        int src = (int)(w & 0x1FFFFu);
        int p = atomicAdd(&lc[d], 1);
        csr_src[base + sc[d] + p] = src;
    }
}

// ---------------- K5: fused gather: single-pass softmax + weighted sum + bias + tanh ----
__global__ __launch_bounds__(256) void gather_kernel(const int* __restrict__ row_start,
                                                     const int* __restrict__ deg,
                                                     const int* __restrict__ csr_src,
                                                     const float* __restrict__ alpha_s,
                                                     const float* __restrict__ alpha_d,
                                                     const unsigned short* __restrict__ h_bf,
                                                     const float* __restrict__ bias,
                                                     float* __restrict__ out, int n) {
    int lane = threadIdx.x & 63;
    int wid  = threadIdx.x >> 6;
    int v = blockIdx.x * 4 + wid;
    if (v >= n) return;
    int start = row_start[v];
    int cnt = deg[v];
    int head = lane >> 4;

    const unsigned* hb = reinterpret_cast<const unsigned*>(h_bf);

    float adH = alpha_d[(size_t)v * 4 + head];
    float asH = alpha_s[(size_t)v * 4 + head];
    float pself = __expf(lrelu(asH + adH));
    unsigned hv0 = hb[((unsigned)v << 6) + lane];
    float s = pself;
    float accx = pself * bf16_lo(hv0);
    float accy = pself * bf16_hi(hv0);

    int j = 0;
    for (; j + 8 <= cnt; j += 8) {
        int s0 = csr_src[start + j + 0];
        int s1 = csr_src[start + j + 1];
        int s2 = csr_src[start + j + 2];
        int s3 = csr_src[start + j + 3];
        int s4 = csr_src[start + j + 4];
        int s5 = csr_src[start + j + 5];
        int s6 = csr_src[start + j + 6];
        int s7 = csr_src[start + j + 7];
        float a0 = alpha_s[(size_t)s0 * 4 + head];
        float a1 = alpha_s[(size_t)s1 * 4 + head];
        float a2 = alpha_s[(size_t)s2 * 4 + head];
        float a3 = alpha_s[(size_t)s3 * 4 + head];
        float a4 = alpha_s[(size_t)s4 * 4 + head];
        float a5 = alpha_s[(size_t)s5 * 4 + head];
        float a6 = alpha_s[(size_t)s6 * 4 + head];
        float a7 = alpha_s[(size_t)s7 * 4 + head];
        unsigned h0 = hb[((unsigned)s0 << 6) + lane];
        unsigned h1 = hb[((unsigned)s1 << 6) + lane];
        unsigned h2 = hb[((unsigned)s2 << 6) + lane];
        unsigned h3 = hb[((unsigned)s3 << 6) + lane];
        unsigned h4 = hb[((unsigned)s4 << 6) + lane];
        unsigned h5 = hb[((unsigned)s5 << 6) + lane];
        unsigned h6 = hb[((unsigned)s6 << 6) + lane];
        unsigned h7 = hb[((unsigned)s7 << 6) + lane];
        float w0 = __expf(lrelu(a0 + adH));
        float w1 = __expf(lrelu(a1 + adH));
        float w2 = __expf(lrelu(a2 + adH));
        float w3 = __expf(lrelu(a3 + adH));
        float w4 = __expf(lrelu(a4 + adH));
        float w5 = __expf(lrelu(a5 + adH));
        float w6 = __expf(lrelu(a6 + adH));
        float w7 = __expf(lrelu(a7 + adH));
        s += w0 + w1 + w2 + w3 + w4 + w5 + w6 + w7;
        accx = fmaf(w0, bf16_lo(h0), accx); accy = fmaf(w0, bf16_hi(h0), accy);
        accx = fmaf(w1, bf16_lo(h1), accx); accy = fmaf(w1, bf16_hi(h1), accy);
        accx = fmaf(w2, bf16_lo(h2), accx); accy = fmaf(w2, bf16_hi(h2), accy);
        accx = fmaf(w3, bf16_lo(h3), accx); accy = fmaf(w3, bf16_hi(h3), accy);
        accx = fmaf(w4, bf16_lo(h4), accx); accy = fmaf(w4, bf16_hi(h4), accy);
        accx = fmaf(w5, bf16_lo(h5), accx); accy = fmaf(w5, bf16_hi(h5), accy);
        accx = fmaf(w6, bf16_lo(h6), accx); accy = fmaf(w6, bf16_hi(h6), accy);
        accx = fmaf(w7, bf16_lo(h7), accx); accy = fmaf(w7, bf16_hi(h7), accy);
    }
    for (; j + 4 <= cnt; j += 4) {
        int s0 = csr_src[start + j + 0];
        int s1 = csr_src[start + j + 1];
        int s2 = csr_src[start + j + 2];
        int s3 = csr_src[start + j + 3];
        float a0 = alpha_s[(size_t)s0 * 4 + head];
        float a1 = alpha_s[(size_t)s1 * 4 + head];
        float a2 = alpha_s[(size_t)s2 * 4 + head];
        float a3 = alpha_s[(size_t)s3 * 4 + head];
        unsigned h0 = hb[((unsigned)s0 << 6) + lane];
        unsigned h1 = hb[((unsigned)s1 << 6) + lane];
        unsigned h2 = hb[((unsigned)s2 << 6) + lane];
        unsigned h3 = hb[((unsigned)s3 << 6) + lane];
        float w0 = __expf(lrelu(a0 + adH));
        float w1 = __expf(lrelu(a1 + adH));
        float w2 = __expf(lrelu(a2 + adH));
        float w3 = __expf(lrelu(a3 + adH));
        s += w0 + w1 + w2 + w3;
        accx = fmaf(w0, bf16_lo(h0), accx); accy = fmaf(w0, bf16_hi(h0), accy);
        accx = fmaf(w1, bf16_lo(h1), accx); accy = fmaf(w1, bf16_hi(h1), accy);
        accx = fmaf(w2, bf16_lo(h2), accx); accy = fmaf(w2, bf16_hi(h2), accy);
        accx = fmaf(w3, bf16_lo(h3), accx); accy = fmaf(w3, bf16_hi(h3), accy);
    }
    for (; j < cnt; ++j) {
        int s0 = csr_src[start + j];
        float a0 = alpha_s[(size_t)s0 * 4 + head];
        unsigned h0 = hb[((unsigned)s0 << 6) + lane];
        float w0 = __expf(lrelu(a0 + adH));
        s += w0;
        accx = fmaf(w0, bf16_lo(h0), accx);
        accy = fmaf(w0, bf16_hi(h0), accy);
    }

    float invH = __builtin_amdgcn_rcpf(s + 1e-16f);
    float2 b = reinterpret_cast<const float2*>(bias)[lane];
    float2 o;
    o.x = fast_tanh(fmaf(accx, invH, b.x));
    o.y = fast_tanh(fmaf(accy, invH, b.y));
    reinterpret_cast<float2*>(out)[(size_t)v * 64 + lane] = o;
}

extern "C" void kernel_launch(void* const* d_in, const int* in_sizes, int n_in,
                              void* d_out, int out_size, void* d_ws, size_t ws_size,
                              hipStream_t stream) {
    const float* x     = (const float*)d_in[0];
    const float* W     = (const float*)d_in[1];
    const float* a_src = (const float*)d_in[2];
    const float* a_dst = (const float*)d_in[3];
    const float* bias  = (const float*)d_in[4];
    const int*   ei    = (const int*)d_in[5];

    const int n = in_sizes[0] / IN_DIM;        // 100000
    const int E = in_sizes[5] / 2;             // 1000000
    const int nb = (n + BKT - 1) / BKT;        // 98

    float* ws = (float*)d_ws;
    size_t off = 0;
    unsigned short* h_bf = (unsigned short*)(ws + off); off += (size_t)n * HC / 2;
    float* alpha_s = ws + off; off += (size_t)n * NHEAD;
    float* alpha_d = ws + off; off += (size_t)n * NHEAD;
    unsigned short* w_hi = (unsigned short*)(ws + off); off += 16384;
    int* ibase        = (int*)(ws + off);
    int* deg          = ibase;                        // n
    int* row_start    = ibase + n;                    // n
    int* bucket_cnt   = ibase + 2 * (size_t)n;        // NBMAX
    int* bucket_base  = bucket_cnt + NBMAX;           // NBMAX+1
    int* bucket_cursor= bucket_base + NBMAX + 1;      // NBMAX
    unsigned* bucket_data = (unsigned*)(bucket_cursor + NBMAX);  // E
    int* csr_src      = (int*)(bucket_data + E);      // E

    float* out = (float*)d_out;

    const int nblkE = (E + BE - 1) / BE;              // 245
    const int gemmB = (n + 63) / 64;                  // 1563

    hipMemsetAsync(bucket_cnt, 0, NBMAX * sizeof(int), stream);

    pack_hist_kernel<<<PACKB + nblkE, 256, 0, stream>>>(W, w_hi, ei, bucket_cnt, E, nb);
    bucket_scan_kernel<<<1, 128, 0, stream>>>(bucket_cnt, bucket_base, bucket_cursor, nb);
    scatter_gemm_kernel<<<nblkE + gemmB, 512, 0, stream>>>(ei, bucket_cursor, bucket_data,
                                                           E, nb, nblkE,
                                                           x, w_hi, a_src, a_dst,
                                                           h_bf, alpha_s, alpha_d, n);
    bucket_build_kernel<<<nb, 1024, 0, stream>>>(bucket_base, bucket_data,
                                                 deg, row_start, csr_src, n);

    gather_kernel<<<(n + 3) / 4, 256, 0, stream>>>(row_start, deg, csr_src,
                                                   alpha_s, alpha_d, h_bf, bias, out, n);
}